// Round 7
// baseline (670.082 us; speedup 1.0000x reference)
//
#include <hip/hip_runtime.h>

#define TT 5
#define HH 384
#define WW 384
#define CC 3
#define WSR 4
#define NH_ 96
#define NW_ 96
#define NQ_ (TT*NH_*NW_)   // 46080
#define NCAND 243
#define KK 10

#define RROW 12            // region row stride (dwords): 8 data (16 cols f16) + 4 pad
#define RSST 13            // rowssd row stride (floats): 10 data + 3 pad

typedef _Float16 h2v __attribute__((ext_vector_type(2)));
union U32H2 { unsigned u; h2v h; };

// RNE packing (cvt_pkrtz is round-toward-zero -> biased distances; R5 post-mortem)
static __device__ __forceinline__ unsigned pack_f16(float a, float b) {
    U32H2 u;
    u.h.x = (_Float16)a; u.h.y = (_Float16)b;   // v_cvt_f16_f32 = RNE
    return u.u;
}

// Wave-64 min via DPP: row_ror 1/2/4/8 -> per-16-row min; bcast15/31 fold rows.
// Lane 63 holds the wave min.
static __device__ __forceinline__ unsigned wave_min63(unsigned x) {
    x = min(x, (unsigned)__builtin_amdgcn_update_dpp((int)x,(int)x,0x121,0xF,0xF,false));
    x = min(x, (unsigned)__builtin_amdgcn_update_dpp((int)x,(int)x,0x122,0xF,0xF,false));
    x = min(x, (unsigned)__builtin_amdgcn_update_dpp((int)x,(int)x,0x124,0xF,0xF,false));
    x = min(x, (unsigned)__builtin_amdgcn_update_dpp((int)x,(int)x,0x128,0xF,0xF,false));
    x = min(x, (unsigned)__builtin_amdgcn_update_dpp((int)x,(int)x,0x142,0xF,0xF,false));
    x = min(x, (unsigned)__builtin_amdgcn_update_dpp((int)x,(int)x,0x143,0xF,0xF,false));
    return x;
}

// One block (256 threads) per query; blockIdx XCD-swizzled so each XCD's
// 5760 consecutive queries (60 hi-rows) keep a ~3.4MB working set in its 4MB L2.
__global__ __launch_bounds__(256) void nls_kernel(
    const float* __restrict__ vid,    // noisy [T,C,H,W]
    const float* __restrict__ fflow,  // [T,2,H,W], ch0=x/w, ch1=y/h
    const float* __restrict__ bflow,
    float* __restrict__ out)          // single scalar, atomically accumulated
{
    const int bid = blockIdx.x;
    const int q   = (bid & 7) * (NQ_/8) + (bid >> 3);   // bijective: NQ_%8==0
    const int tid = threadIdx.x;
    const int t   = q / (NH_*NW_);
    const int rem = q % (NH_*NW_);
    const int hi  = (rem / NW_) * 4;
    const int wi  = (rem % NW_) * 4;

    __shared__ alignas(16) unsigned reg_lds[135*RROW];  // 3di*3c*15 rows
    __shared__ alignas(16) unsigned qp_lds[84];         // [c][7][4] dwords
    __shared__ alignas(16) float    rssd[189*RSST];     // [di][roff][dy][wof]
    __shared__ float dist[256];

    const float ffx = fflow[((t*2+0)*HH + hi)*WW + wi];
    const float ffy = fflow[((t*2+1)*HH + hi)*WW + wi];
    const float bfx = bflow[((t*2+0)*HH + hi)*WW + wi];
    const float bfy = bflow[((t*2+1)*HH + hi)*WW + wi];

    // dt order: [-1 (bflow), 0, +1 (fflow)]
    const int tj0 = max(t-1, 0);
    const int tj2 = min(t+1, TT-1);
    const int bh0 = min(max(hi + (int)rintf(bfy), 0), HH-1);
    const int bw0 = min(max(wi + (int)rintf(bfx), 0), WW-1);
    const int bh2 = min(max(hi + (int)rintf(ffy), 0), HH-1);
    const int bw2 = min(max(wi + (int)rintf(ffx), 0), WW-1);
    const int rm0 = max(bh0-WSR,0), rm1 = max(hi-WSR,0), rm2 = max(bh2-WSR,0);
    const int cm0 = max(bw0-WSR,0), cm1 = max(wi-WSR,0), cm2 = max(bw2-WSR,0);
    const int ca0 = cm0 & ~1,       ca1 = cm1 & ~1,      ca2 = cm2 & ~1;

    // ---- Stage region: 135 rows x 16 cols, 2 half-rows (8 cols) per item ----
    for (int i = tid; i < 270; i += 256) {
        int row = i >> 1, h = i & 1;
        int di  = row / 45; int r45 = row - di*45;
        int c   = r45 / 15; int r   = r45 - c*15;
        int tjd = (di==0)?tj0:((di==1)?t  :tj2);
        int rm  = (di==0)?rm0:((di==1)?rm1:rm2);
        int ca  = (di==0)?ca0:((di==1)?ca1:ca2);
        int rr  = min(rm + r, HH-1);
        const float* vrow = vid + (size_t)((tjd*CC+c)*HH + rr)*WW;
        int c0 = ca + 8*h;
        float f0,f1,f2,f3,f4,f5,f6,f7;
        if (ca <= 368) {                     // cols ca..ca+15 in-bounds; ca even
            float2 p0 = *(const float2*)(vrow + c0);
            float2 p1 = *(const float2*)(vrow + c0 + 2);
            float2 p2 = *(const float2*)(vrow + c0 + 4);
            float2 p3 = *(const float2*)(vrow + c0 + 6);
            f0=p0.x; f1=p0.y; f2=p1.x; f3=p1.y; f4=p2.x; f5=p2.y; f6=p3.x; f7=p3.y;
        } else {
            f0=vrow[min(c0,  WW-1)]; f1=vrow[min(c0+1,WW-1)];
            f2=vrow[min(c0+2,WW-1)]; f3=vrow[min(c0+3,WW-1)];
            f4=vrow[min(c0+4,WW-1)]; f5=vrow[min(c0+5,WW-1)];
            f6=vrow[min(c0+6,WW-1)]; f7=vrow[min(c0+7,WW-1)];
        }
        uint4 w;
        w.x = pack_f16(f0,f1); w.y = pack_f16(f2,f3);
        w.z = pack_f16(f4,f5); w.w = pack_f16(f6,f7);
        *(uint4*)&reg_lds[row*RROW + 4*h] = w;
    }
    // ---- Stage query patch (pairs (wi+2k, wi+2k+1); k=3 high half = 0) ----
    if (tid < 84) {
        int c  = tid / 28;
        int rr = tid - c*28;
        int dy = rr >> 2;
        int k  = rr & 3;
        int row = min(hi+dy, HH-1);
        const float* vrow = vid + (size_t)((t*CC + c)*HH + row)*WW;
        float v0 = vrow[min(wi + 2*k, WW-1)];
        float v1 = (k==3) ? 0.0f : vrow[min(wi + 2*k + 1, WW-1)];
        qp_lds[tid] = pack_f16(v0, v1);
    }
    __syncthreads();

    // ---- Phase R: 189 threads, each (di,roff,dy): row-SSD for wof=0..9 ----
    if (tid < 189) {
        int di   = tid / 63; int r63 = tid - di*63;
        int roff = r63 / 7;  int dy  = r63 - roff*7;
        int rr   = roff + dy;                      // 0..14
        float rs[10];
        #pragma unroll
        for (int w = 0; w < 10; w++) rs[w] = 0.f;
        #pragma unroll
        for (int c = 0; c < 3; c++) {
            int base = ((di*3 + c)*15 + rr)*RROW;
            uint4 va0 = *(const uint4*)&reg_lds[base];
            uint4 va1 = *(const uint4*)&reg_lds[base + 4];
            uint4 vq  = *(const uint4*)&qp_lds[c*28 + dy*4];
            unsigned A[8], B[8];
            A[0]=va0.x; A[1]=va0.y; A[2]=va0.z; A[3]=va0.w;
            A[4]=va1.x; A[5]=va1.y; A[6]=va1.z; A[7]=va1.w;
            #pragma unroll
            for (int j = 0; j < 7; j++) B[j] = (A[j] >> 16) | (A[j+1] << 16);  // v_alignbit
            B[7] = A[7] >> 16;
            U32H2 q0,q1,q2,q3;
            q0.u = vq.x; q1.u = vq.y; q2.u = vq.z; q3.u = vq.w;
            #pragma unroll
            for (int w = 0; w < 10; w++) {
                const int off = w >> 1;
                U32H2 c0,c1,c2,c3;
                if (w & 1) { c0.u=B[off]; c1.u=B[off+1]; c2.u=B[off+2]; c3.u=B[off+3]; }
                else       { c0.u=A[off]; c1.u=A[off+1]; c2.u=A[off+2]; c3.u=A[off+3]; }
                U32H2 d0,d1,d2,d3;
                d0.h = c0.h - q0.h;
                d1.h = c1.h - q1.h;
                d2.h = c2.h - q2.h;
                d3.h = c3.h - q3.h;
                d3.u &= 0x0000FFFFu;               // exclude col wof+7
                float s = rs[w];
                s = __builtin_amdgcn_fdot2(d0.h, d0.h, s, false);
                s = __builtin_amdgcn_fdot2(d1.h, d1.h, s, false);
                s = __builtin_amdgcn_fdot2(d2.h, d2.h, s, false);
                s = __builtin_amdgcn_fdot2(d3.h, d3.h, s, false);
                rs[w] = s;
            }
        }
        int ob = tid * RSST;
        #pragma unroll
        for (int w = 0; w < 10; w++) rssd[ob + w] = rs[w];
    }
    __syncthreads();

    // ---- Phase F: 243 candidates, each sums 7 row-SSDs ----
    float dmy = __int_as_float(0x7f800000);
    if (tid < NCAND) {
        int di  = tid / 81; int s81 = tid - di*81;
        int syq = s81 / 9;  int sx  = s81 - syq*9 - WSR;
        int sy  = syq - WSR;
        int bhd = (di==0)?bh0:((di==1)?hi :bh2);
        int bwd = (di==0)?bw0:((di==1)?wi :bw2);
        int rm  = (di==0)?rm0:((di==1)?rm1:rm2);
        int ca  = (di==0)?ca0:((di==1)?ca1:ca2);
        int hj = min(max(bhd + sy, 0), HH-1);
        int wj = min(max(bwd + sx, 0), WW-1);
        int roff = hj - rm;                 // 0..8
        int wof  = wj - ca;                 // 0..9
        int ib = (di*63 + roff*7)*RSST + wof;
        float s = 0.f;
        #pragma unroll
        for (int dy = 0; dy < 7; dy++) s += rssd[ib + dy*RSST];
        dmy = s;                            // sum of squares: >= 0
    }
    dist[tid] = dmy;
    __syncthreads();

    // ---- Top-10 smallest of 243: DPP wave-argmin on packed keys.
    // Winner value taken from truncated key bits (rel err <= 2^-16; total
    // output bias < 0.03 vs threshold 3.96) -> no readlane value fetch.
    if (tid < 64) {
        unsigned k0 = (__float_as_uint(dist[tid    ]) & 0xFFFFFF00u) | (unsigned)tid;
        unsigned k1 = (__float_as_uint(dist[tid+ 64]) & 0xFFFFFF00u) | (unsigned)(tid+64);
        unsigned k2 = (__float_as_uint(dist[tid+128]) & 0xFFFFFF00u) | (unsigned)(tid+128);
        unsigned k3 = (__float_as_uint(dist[tid+192]) & 0xFFFFFF00u) | (unsigned)(tid+192);
        float sumk = 0.f;
        #pragma unroll 1
        for (int k = 0; k < KK; k++) {
            unsigned loc = min(min(k0,k1), min(k2,k3));
            unsigned wm  = wave_min63(loc);
            unsigned m   = (unsigned)__builtin_amdgcn_readlane((int)wm, 63); // uniform
            sumk += __uint_as_float(m & 0xFFFFFF00u);
            int slot = (int)(m & 0xFFu);
            // kill the selected slot (slots distinct even for duplicate values)
            k0 = (slot == (int)tid      ) ? 0xFFFFFFFFu : k0;
            k1 = (slot == (int)tid + 64 ) ? 0xFFFFFFFFu : k1;
            k2 = (slot == (int)tid + 128) ? 0xFFFFFFFFu : k2;
            k3 = (slot == (int)tid + 192) ? 0xFFFFFFFFu : k3;
        }
        if (tid == 0)
            atomicAdd(out, sumk * (1.0f / ((float)NQ_ * (float)KK)));
    }
}

extern "C" void kernel_launch(void* const* d_in, const int* in_sizes, int n_in,
                              void* d_out, int out_size, void* d_ws, size_t ws_size,
                              hipStream_t stream) {
    const float* noisy = (const float*)d_in[0];
    // d_in[1] = deno: unused (SEARCH_INPUT='noisy', refine also uses noisy)
    const float* fflow = (const float*)d_in[2];
    const float* bflow = (const float*)d_in[3];
    float* out = (float*)d_out;

    hipMemsetAsync(out, 0, sizeof(float), stream);   // capture-safe
    nls_kernel<<<NQ_, 256, 0, stream>>>(noisy, fflow, bflow, out);
}

// Round 8
// 268.978 us; speedup vs baseline: 2.4912x; 2.4912x over previous
//
#include <hip/hip_runtime.h>

#define TT 5
#define HH 384
#define WW 384
#define CC 3
#define WSR 4
#define NH_ 96
#define NW_ 96
#define NQ_ (TT*NH_*NW_)   // 46080
#define NCAND 243
#define KK 10

#define RROW 12            // region row stride (dwords): 8 data (16 cols f16) + 4 pad
#define RSST 13            // rowssd row stride (floats): 10 data + 3 pad

typedef _Float16 h2v __attribute__((ext_vector_type(2)));
union U32H2 { unsigned u; h2v h; };

// RNE packing (cvt_pkrtz is round-toward-zero -> biased distances; R5 post-mortem)
static __device__ __forceinline__ unsigned pack_f16(float a, float b) {
    U32H2 u;
    u.h.x = (_Float16)a; u.h.y = (_Float16)b;   // v_cvt_f16_f32 = RNE
    return u.u;
}

// Wave-64 min via DPP: row_ror 1/2/4/8 -> per-16-row min; bcast15/31 fold rows.
// Lane 63 holds the wave min.
static __device__ __forceinline__ unsigned wave_min63(unsigned x) {
    x = min(x, (unsigned)__builtin_amdgcn_update_dpp((int)x,(int)x,0x121,0xF,0xF,false));
    x = min(x, (unsigned)__builtin_amdgcn_update_dpp((int)x,(int)x,0x122,0xF,0xF,false));
    x = min(x, (unsigned)__builtin_amdgcn_update_dpp((int)x,(int)x,0x124,0xF,0xF,false));
    x = min(x, (unsigned)__builtin_amdgcn_update_dpp((int)x,(int)x,0x128,0xF,0xF,false));
    x = min(x, (unsigned)__builtin_amdgcn_update_dpp((int)x,(int)x,0x142,0xF,0xF,false));
    x = min(x, (unsigned)__builtin_amdgcn_update_dpp((int)x,(int)x,0x143,0xF,0xF,false));
    return x;
}

// One block (256 threads) per query; blockIdx XCD-swizzled so each XCD's
// 5760 consecutive queries (60 hi-rows) keep a ~3.4MB working set in its 4MB L2
// (R7: FETCH_SIZE 95MB -> 14.7MB). Result per query -> ws[q]; tiny reduce after
// (R7 lesson: 46080 same-address atomics serialize to ~600us).
__global__ __launch_bounds__(256) void nls_kernel(
    const float* __restrict__ vid,    // noisy [T,C,H,W]
    const float* __restrict__ fflow,  // [T,2,H,W], ch0=x/w, ch1=y/h
    const float* __restrict__ bflow,
    float* __restrict__ ws)           // [NQ_] per-query top-K sums
{
    const int bid = blockIdx.x;
    const int q   = (bid & 7) * (NQ_/8) + (bid >> 3);   // bijective: NQ_%8==0
    const int tid = threadIdx.x;
    const int t   = q / (NH_*NW_);
    const int rem = q % (NH_*NW_);
    const int hi  = (rem / NW_) * 4;
    const int wi  = (rem % NW_) * 4;

    __shared__ alignas(16) unsigned reg_lds[135*RROW];  // 3di*3c*15 rows
    __shared__ alignas(16) unsigned qp_lds[84];         // [c][7][4] dwords
    __shared__ alignas(16) float    rssd[189*RSST];     // [di][roff][dy][wof]
    __shared__ float dist[256];

    const float ffx = fflow[((t*2+0)*HH + hi)*WW + wi];
    const float ffy = fflow[((t*2+1)*HH + hi)*WW + wi];
    const float bfx = bflow[((t*2+0)*HH + hi)*WW + wi];
    const float bfy = bflow[((t*2+1)*HH + hi)*WW + wi];

    // dt order: [-1 (bflow), 0, +1 (fflow)]
    const int tj0 = max(t-1, 0);
    const int tj2 = min(t+1, TT-1);
    const int bh0 = min(max(hi + (int)rintf(bfy), 0), HH-1);
    const int bw0 = min(max(wi + (int)rintf(bfx), 0), WW-1);
    const int bh2 = min(max(hi + (int)rintf(ffy), 0), HH-1);
    const int bw2 = min(max(wi + (int)rintf(ffx), 0), WW-1);
    const int rm0 = max(bh0-WSR,0), rm1 = max(hi-WSR,0), rm2 = max(bh2-WSR,0);
    const int cm0 = max(bw0-WSR,0), cm1 = max(wi-WSR,0), cm2 = max(bw2-WSR,0);
    const int ca0 = cm0 & ~1,       ca1 = cm1 & ~1,      ca2 = cm2 & ~1;

    // ---- Stage region: 135 rows x 16 cols, 2 half-rows (8 cols) per item ----
    for (int i = tid; i < 270; i += 256) {
        int row = i >> 1, h = i & 1;
        int di  = row / 45; int r45 = row - di*45;
        int c   = r45 / 15; int r   = r45 - c*15;
        int tjd = (di==0)?tj0:((di==1)?t  :tj2);
        int rm  = (di==0)?rm0:((di==1)?rm1:rm2);
        int ca  = (di==0)?ca0:((di==1)?ca1:ca2);
        int rr  = min(rm + r, HH-1);
        const float* vrow = vid + (size_t)((tjd*CC+c)*HH + rr)*WW;
        int c0 = ca + 8*h;
        float f0,f1,f2,f3,f4,f5,f6,f7;
        if (ca <= 368) {                     // cols ca..ca+15 in-bounds; ca even
            float2 p0 = *(const float2*)(vrow + c0);
            float2 p1 = *(const float2*)(vrow + c0 + 2);
            float2 p2 = *(const float2*)(vrow + c0 + 4);
            float2 p3 = *(const float2*)(vrow + c0 + 6);
            f0=p0.x; f1=p0.y; f2=p1.x; f3=p1.y; f4=p2.x; f5=p2.y; f6=p3.x; f7=p3.y;
        } else {
            f0=vrow[min(c0,  WW-1)]; f1=vrow[min(c0+1,WW-1)];
            f2=vrow[min(c0+2,WW-1)]; f3=vrow[min(c0+3,WW-1)];
            f4=vrow[min(c0+4,WW-1)]; f5=vrow[min(c0+5,WW-1)];
            f6=vrow[min(c0+6,WW-1)]; f7=vrow[min(c0+7,WW-1)];
        }
        uint4 w;
        w.x = pack_f16(f0,f1); w.y = pack_f16(f2,f3);
        w.z = pack_f16(f4,f5); w.w = pack_f16(f6,f7);
        *(uint4*)&reg_lds[row*RROW + 4*h] = w;
    }
    // ---- Stage query patch (pairs (wi+2k, wi+2k+1); k=3 high half = 0) ----
    if (tid < 84) {
        int c  = tid / 28;
        int rr = tid - c*28;
        int dy = rr >> 2;
        int k  = rr & 3;
        int row = min(hi+dy, HH-1);
        const float* vrow = vid + (size_t)((t*CC + c)*HH + row)*WW;
        float v0 = vrow[min(wi + 2*k, WW-1)];
        float v1 = (k==3) ? 0.0f : vrow[min(wi + 2*k + 1, WW-1)];
        qp_lds[tid] = pack_f16(v0, v1);
    }
    __syncthreads();

    // ---- Phase R: 189 threads, each (di,roff,dy): row-SSD for wof=0..9 ----
    if (tid < 189) {
        int di   = tid / 63; int r63 = tid - di*63;
        int roff = r63 / 7;  int dy  = r63 - roff*7;
        int rr   = roff + dy;                      // 0..14
        float rs[10];
        #pragma unroll
        for (int w = 0; w < 10; w++) rs[w] = 0.f;
        #pragma unroll
        for (int c = 0; c < 3; c++) {
            int base = ((di*3 + c)*15 + rr)*RROW;
            uint4 va0 = *(const uint4*)&reg_lds[base];
            uint4 va1 = *(const uint4*)&reg_lds[base + 4];
            uint4 vq  = *(const uint4*)&qp_lds[c*28 + dy*4];
            unsigned A[8], B[8];
            A[0]=va0.x; A[1]=va0.y; A[2]=va0.z; A[3]=va0.w;
            A[4]=va1.x; A[5]=va1.y; A[6]=va1.z; A[7]=va1.w;
            #pragma unroll
            for (int j = 0; j < 7; j++) B[j] = (A[j] >> 16) | (A[j+1] << 16);  // v_alignbit
            B[7] = A[7] >> 16;
            U32H2 q0,q1,q2,q3;
            q0.u = vq.x; q1.u = vq.y; q2.u = vq.z; q3.u = vq.w;
            #pragma unroll
            for (int w = 0; w < 10; w++) {
                const int off = w >> 1;
                U32H2 c0,c1,c2,c3;
                if (w & 1) { c0.u=B[off]; c1.u=B[off+1]; c2.u=B[off+2]; c3.u=B[off+3]; }
                else       { c0.u=A[off]; c1.u=A[off+1]; c2.u=A[off+2]; c3.u=A[off+3]; }
                U32H2 d0,d1,d2,d3;
                d0.h = c0.h - q0.h;
                d1.h = c1.h - q1.h;
                d2.h = c2.h - q2.h;
                d3.h = c3.h - q3.h;
                d3.u &= 0x0000FFFFu;               // exclude col wof+7
                float s = rs[w];
                s = __builtin_amdgcn_fdot2(d0.h, d0.h, s, false);
                s = __builtin_amdgcn_fdot2(d1.h, d1.h, s, false);
                s = __builtin_amdgcn_fdot2(d2.h, d2.h, s, false);
                s = __builtin_amdgcn_fdot2(d3.h, d3.h, s, false);
                rs[w] = s;
            }
        }
        int ob = tid * RSST;
        #pragma unroll
        for (int w = 0; w < 10; w++) rssd[ob + w] = rs[w];
    }
    __syncthreads();

    // ---- Phase F: 243 candidates, each sums 7 row-SSDs ----
    float dmy = __int_as_float(0x7f800000);
    if (tid < NCAND) {
        int di  = tid / 81; int s81 = tid - di*81;
        int syq = s81 / 9;  int sx  = s81 - syq*9 - WSR;
        int sy  = syq - WSR;
        int bhd = (di==0)?bh0:((di==1)?hi :bh2);
        int bwd = (di==0)?bw0:((di==1)?wi :bw2);
        int rm  = (di==0)?rm0:((di==1)?rm1:rm2);
        int ca  = (di==0)?ca0:((di==1)?ca1:ca2);
        int hj = min(max(bhd + sy, 0), HH-1);
        int wj = min(max(bwd + sx, 0), WW-1);
        int roff = hj - rm;                 // 0..8
        int wof  = wj - ca;                 // 0..9
        int ib = (di*63 + roff*7)*RSST + wof;
        float s = 0.f;
        #pragma unroll
        for (int dy = 0; dy < 7; dy++) s += rssd[ib + dy*RSST];
        dmy = s;                            // sum of squares: >= 0
    }
    dist[tid] = dmy;
    __syncthreads();

    // ---- Top-10 smallest of 243: DPP wave-argmin on packed keys.
    // Winner value from truncated key bits (rel err <= 2^-16; output bias
    // < 0.03 vs threshold 3.96).
    if (tid < 64) {
        unsigned k0 = (__float_as_uint(dist[tid    ]) & 0xFFFFFF00u) | (unsigned)tid;
        unsigned k1 = (__float_as_uint(dist[tid+ 64]) & 0xFFFFFF00u) | (unsigned)(tid+64);
        unsigned k2 = (__float_as_uint(dist[tid+128]) & 0xFFFFFF00u) | (unsigned)(tid+128);
        unsigned k3 = (__float_as_uint(dist[tid+192]) & 0xFFFFFF00u) | (unsigned)(tid+192);
        float sumk = 0.f;
        #pragma unroll 1
        for (int k = 0; k < KK; k++) {
            unsigned loc = min(min(k0,k1), min(k2,k3));
            unsigned wm  = wave_min63(loc);
            unsigned m   = (unsigned)__builtin_amdgcn_readlane((int)wm, 63); // uniform
            sumk += __uint_as_float(m & 0xFFFFFF00u);
            int slot = (int)(m & 0xFFu);
            // kill the selected slot (slots distinct even for duplicate values)
            k0 = (slot == (int)tid      ) ? 0xFFFFFFFFu : k0;
            k1 = (slot == (int)tid + 64 ) ? 0xFFFFFFFFu : k1;
            k2 = (slot == (int)tid + 128) ? 0xFFFFFFFFu : k2;
            k3 = (slot == (int)tid + 192) ? 0xFFFFFFFFu : k3;
        }
        if (tid == 0) ws[q] = sumk;
    }
}

// 180 blocks x 256: partial sums + one scaled atomicAdd per block.
__global__ __launch_bounds__(256) void reduce1_kernel(
    const float* __restrict__ ws, float* __restrict__ out)
{
    float s = ws[blockIdx.x*256 + threadIdx.x];
    #pragma unroll
    for (int o = 32; o > 0; o >>= 1) s += __shfl_down(s, o, 64);
    __shared__ float sd[4];
    int w = threadIdx.x >> 6, l = threadIdx.x & 63;
    if (l == 0) sd[w] = s;
    __syncthreads();
    if (threadIdx.x == 0) {
        float tot = sd[0] + sd[1] + sd[2] + sd[3];
        atomicAdd(out, tot * (1.0f / ((float)NQ_ * (float)KK)));
    }
}

extern "C" void kernel_launch(void* const* d_in, const int* in_sizes, int n_in,
                              void* d_out, int out_size, void* d_ws, size_t ws_size,
                              hipStream_t stream) {
    const float* noisy = (const float*)d_in[0];
    // d_in[1] = deno: unused (SEARCH_INPUT='noisy', refine also uses noisy)
    const float* fflow = (const float*)d_in[2];
    const float* bflow = (const float*)d_in[3];
    float* ws  = (float*)d_ws;
    float* out = (float*)d_out;

    hipMemsetAsync(out, 0, sizeof(float), stream);   // capture-safe
    nls_kernel<<<NQ_, 256, 0, stream>>>(noisy, fflow, bflow, ws);
    reduce1_kernel<<<NQ_/256, 256, 0, stream>>>(ws, out);
}